// Round 1
// baseline (1024.620 us; speedup 1.0000x reference)
//
#include <hip/hip_runtime.h>
#include <hip/hip_bf16.h>

typedef __attribute__((ext_vector_type(8))) short short8_t;
typedef __attribute__((ext_vector_type(4))) float float4_t;

#define D_DIM 768
#define S_DIM 4096
#define B_DIM 4
#define M_DIM (B_DIM * S_DIM)  // 16384

__device__ __forceinline__ short f2bf(float f) {
  unsigned u = __float_as_uint(f);
  unsigned r = (u + 0x7fffu + ((u >> 16) & 1u)) >> 16;  // RNE
  return (short)r;
}

// ---------------- x -> bf16 (vectorized) ----------------
__global__ __launch_bounds__(256) void cvt_x_kernel(const float* __restrict__ in,
                                                    short* __restrict__ out, int n) {
  int i = (blockIdx.x * 256 + threadIdx.x) * 4;
  if (i < n) {
    float4 v = *(const float4*)(in + i);
    short4 o;
    o.x = f2bf(v.x); o.y = f2bf(v.y); o.z = f2bf(v.z); o.w = f2bf(v.w);
    *(short4*)(out + i) = o;
  }
}

// ---------------- W (fp32 [k][n]) -> WT (bf16 [n][k]) ----------------
__global__ __launch_bounds__(256) void transpose_w_kernel(const float* __restrict__ W0,
                                                          const float* __restrict__ W1,
                                                          const float* __restrict__ W2,
                                                          short* __restrict__ WT) {
  const float* W = (blockIdx.z == 0) ? W0 : (blockIdx.z == 1) ? W1 : W2;
  short* o = WT + (size_t)blockIdx.z * D_DIM * D_DIM;
  __shared__ short tile[64][68];
  int k0 = blockIdx.x * 64, n0 = blockIdx.y * 64;
#pragma unroll
  for (int i = 0; i < 16; ++i) {
    int idx = threadIdx.x + i * 256;
    int r = idx >> 6, c = idx & 63;
    tile[r][c] = f2bf(W[(size_t)(k0 + r) * D_DIM + n0 + c]);
  }
  __syncthreads();
#pragma unroll
  for (int i = 0; i < 16; ++i) {
    int idx = threadIdx.x + i * 256;
    int r = idx >> 6, c = idx & 63;
    o[(size_t)(n0 + r) * D_DIM + k0 + c] = tile[c][r];
  }
}

// ---------------- V (bf16 [s][d]) -> VT (bf16 [d][s]) per batch ----------------
__global__ __launch_bounds__(256) void transpose_v_kernel(const short* __restrict__ Vb,
                                                          short* __restrict__ VTb) {
  __shared__ short tile[64][68];
  int b = blockIdx.z;
  int s0 = blockIdx.x * 64, d0 = blockIdx.y * 64;
  const short* in = Vb + (size_t)b * S_DIM * D_DIM;
  short* o = VTb + (size_t)b * D_DIM * S_DIM;
#pragma unroll
  for (int i = 0; i < 16; ++i) {
    int idx = threadIdx.x + i * 256;
    int rr = idx >> 6, cc = idx & 63;
    tile[rr][cc] = in[(size_t)(s0 + rr) * D_DIM + d0 + cc];
  }
  __syncthreads();
#pragma unroll
  for (int i = 0; i < 16; ++i) {
    int idx = threadIdx.x + i * 256;
    int rr = idx >> 6, cc = idx & 63;
    o[(size_t)(d0 + rr) * S_DIM + s0 + cc] = tile[cc][rr];
  }
}

// ---------------- projections: Y[z] = xb @ WT[z]^T  (bf16 MFMA) ----------------
// grid (M/128, N/128, 3), 256 threads (4 waves, each 64x64 = 4x4 frags)
__global__ __launch_bounds__(256, 2) void proj_kernel(const short* __restrict__ xb,
                                                      const short* __restrict__ WTall,
                                                      short* __restrict__ Yall) {
  const short* WT = WTall + (size_t)blockIdx.z * D_DIM * D_DIM;
  short* Y = Yall + (size_t)blockIdx.z * (size_t)M_DIM * D_DIM;
  int bm = blockIdx.x * 128, bn = blockIdx.y * 128;
  int tid = threadIdx.x;
  int w = tid >> 6, l = tid & 63;
  int wr = w >> 1, wc = w & 1;
  int l15 = l & 15, l4 = l >> 4;
  const float4_t fzero = {0.f, 0.f, 0.f, 0.f};
  float4_t acc[4][4];
#pragma unroll
  for (int a = 0; a < 4; ++a)
#pragma unroll
    for (int bb = 0; bb < 4; ++bb) acc[a][bb] = fzero;
  const short* arow = xb + (size_t)(bm + wr * 64 + l15) * D_DIM + l4 * 8;
  const short* brow = WT + (size_t)(bn + wc * 64 + l15) * D_DIM + l4 * 8;
#pragma unroll 2
  for (int kk = 0; kk < 24; ++kk) {
    short8_t af[4], bf[4];
#pragma unroll
    for (int i = 0; i < 4; ++i)
      af[i] = *(const short8_t*)(arow + (size_t)i * 16 * D_DIM + kk * 32);
#pragma unroll
    for (int i = 0; i < 4; ++i)
      bf[i] = *(const short8_t*)(brow + (size_t)i * 16 * D_DIM + kk * 32);
#pragma unroll
    for (int mi = 0; mi < 4; ++mi)
#pragma unroll
      for (int ni = 0; ni < 4; ++ni)
        acc[mi][ni] = __builtin_amdgcn_mfma_f32_16x16x32_bf16(af[mi], bf[ni], acc[mi][ni], 0, 0, 0);
  }
#pragma unroll
  for (int mi = 0; mi < 4; ++mi) {
#pragma unroll
    for (int ni = 0; ni < 4; ++ni) {
      int colg = bn + wc * 64 + ni * 16 + l15;
#pragma unroll
      for (int j = 0; j < 4; ++j) {
        int rowg = bm + wr * 64 + mi * 16 + l4 * 4 + j;
        Y[(size_t)rowg * D_DIM + colg] = f2bf(acc[mi][ni][j]);
      }
    }
  }
}

// ---------------- flash attention ----------------
// grid: B*64 blocks (q-tile pairs), 512 threads = 8 waves.
// QBLK=32 (2 row-tiles), KVBLK=64 (4 col-tiles). wave w: r=w>>2, c=w&3.
__global__ __launch_bounds__(512, 2) void flash_kernel(const short* __restrict__ Qb,
                                                       const short* __restrict__ Kb,
                                                       const short* __restrict__ VTb,
                                                       float* __restrict__ out) {
  const float SCALE = 0.036084391824351615f;  // 1/sqrt(768)
  __shared__ __align__(16) short P_lds[32 * 64];
  __shared__ float pmax_s[4][32];
  __shared__ float psum_s[4][32];

  int tid = threadIdx.x;
  int w = tid >> 6;
  int l = tid & 63;
  int r = w >> 2;
  int c = w & 3;
  int l15 = l & 15, l4 = l >> 4;

  int b = blockIdx.x >> 6;
  int pair = blockIdx.x & 63;

  const short* Qbase = Qb + (size_t)b * S_DIM * D_DIM;
  const short* Kbase = Kb + (size_t)b * S_DIM * D_DIM;
  const short* Vtb = VTb + (size_t)b * D_DIM * S_DIM;
  float* obase = out + (size_t)b * S_DIM * D_DIM;

  const float4_t fzero = {0.f, 0.f, 0.f, 0.f};

  for (int half = 0; half < 2; ++half) {
    int qt = half ? (127 - pair) : pair;
    int q0 = qt * 32;

    // Q fragments for this wave's 16 rows, entire D=768, in registers
    short8_t qf[24];
    {
      const short* qrow = Qbase + (size_t)(q0 + r * 16 + l15) * D_DIM + l4 * 8;
#pragma unroll
      for (int kk = 0; kk < 24; ++kk) qf[kk] = *(const short8_t*)(qrow + kk * 32);
    }

    float4_t acc[12];
#pragma unroll
    for (int n = 0; n < 12; ++n) acc[n] = fzero;
    float m_i[4], l_i[4];
#pragma unroll
    for (int j = 0; j < 4; ++j) { m_i[j] = -__builtin_inff(); l_i[j] = 0.f; }

    int tmax = (q0 + 31) >> 6;
    for (int t = 0; t <= tmax; ++t) {
      int kv0 = t * 64;
      // ---- QK^T for this wave's 16x16 score tile, K over D=768 ----
      float4_t s0 = fzero, s1 = fzero;
      const short* krow = Kbase + (size_t)(kv0 + c * 16 + l15) * D_DIM + l4 * 8;
#pragma unroll
      for (int kk = 0; kk < 24; kk += 2) {
        short8_t kf0 = *(const short8_t*)(krow + kk * 32);
        short8_t kf1 = *(const short8_t*)(krow + (kk + 1) * 32);
        s0 = __builtin_amdgcn_mfma_f32_16x16x32_bf16(qf[kk], kf0, s0, 0, 0, 0);
        s1 = __builtin_amdgcn_mfma_f32_16x16x32_bf16(qf[kk + 1], kf1, s1, 0, 0, 0);
      }
      float4_t sc = s0 + s1;
      int colg = kv0 + c * 16 + l15;
#pragma unroll
      for (int j = 0; j < 4; ++j) {
        int rowg = q0 + r * 16 + l4 * 4 + j;
        float sv = sc[j] * SCALE;
        sc[j] = (colg <= rowg) ? sv : -1e30f;
      }
      __syncthreads();  // barrier 1: prev-iter LDS consumers done
      // partial max over 16 cols (reduce across l&15)
      float4_t pm = sc;
#pragma unroll
      for (int d = 1; d < 16; d <<= 1) {
#pragma unroll
        for (int j = 0; j < 4; ++j) pm[j] = fmaxf(pm[j], __shfl_xor(pm[j], d));
      }
      if (l15 == 0) {
#pragma unroll
        for (int j = 0; j < 4; ++j) pmax_s[c][r * 16 + l4 * 4 + j] = pm[j];
      }
      __syncthreads();  // barrier 2
      float alpha[4];
#pragma unroll
      for (int j = 0; j < 4; ++j) {
        int rl = r * 16 + l4 * 4 + j;
        float mn = fmaxf(fmaxf(pmax_s[0][rl], pmax_s[1][rl]),
                         fmaxf(pmax_s[2][rl], pmax_s[3][rl]));
        mn = fmaxf(mn, m_i[j]);
        alpha[j] = __expf(m_i[j] - mn);  // m_i=-inf -> 0
        m_i[j] = mn;
        sc[j] = __expf(sc[j] - mn);  // P value (0 for masked)
      }
      // partial sums over 16 cols
      float4_t ps = sc;
#pragma unroll
      for (int d = 1; d < 16; d <<= 1) {
#pragma unroll
        for (int j = 0; j < 4; ++j) ps[j] += __shfl_xor(ps[j], d);
      }
      if (l15 == 0) {
#pragma unroll
        for (int j = 0; j < 4; ++j) psum_s[c][r * 16 + l4 * 4 + j] = ps[j];
      }
      // write P to LDS (bf16, XOR-swizzled rows)
#pragma unroll
      for (int j = 0; j < 4; ++j) {
        int row = r * 16 + l4 * 4 + j;
        int off = row * 128 + (c * 16 + l15) * 2;
        off ^= (row & 7) << 4;
        *(short*)((char*)P_lds + off) = f2bf(sc[j]);
      }
      __syncthreads();  // barrier 3
      // l update + acc rescale
#pragma unroll
      for (int j = 0; j < 4; ++j) {
        int rl = r * 16 + l4 * 4 + j;
        l_i[j] = l_i[j] * alpha[j] +
                 psum_s[0][rl] + psum_s[1][rl] + psum_s[2][rl] + psum_s[3][rl];
      }
#pragma unroll
      for (int n = 0; n < 12; ++n)
#pragma unroll
        for (int j = 0; j < 4; ++j) acc[n][j] *= alpha[j];
      // ---- PV: this wave covers rows r*16.., cols c*192..c*192+191 ----
      short8_t pa[2];
#pragma unroll
      for (int kk = 0; kk < 2; ++kk) {
        int row = r * 16 + l15;
        int off = row * 128 + (kk * 32 + l4 * 8) * 2;
        off ^= (row & 7) << 4;
        pa[kk] = *(const short8_t*)((char*)P_lds + off);
      }
      const short* vrow = Vtb + (size_t)(c * 192 + l15) * S_DIM + kv0 + l4 * 8;
#pragma unroll
      for (int n = 0; n < 12; ++n) {
        const short* vn = vrow + (size_t)n * 16 * S_DIM;
        short8_t v0 = *(const short8_t*)(vn);
        short8_t v1 = *(const short8_t*)(vn + 32);
        acc[n] = __builtin_amdgcn_mfma_f32_16x16x32_bf16(pa[0], v0, acc[n], 0, 0, 0);
        acc[n] = __builtin_amdgcn_mfma_f32_16x16x32_bf16(pa[1], v1, acc[n], 0, 0, 0);
      }
    }
    // epilogue: out = acc / l
#pragma unroll
    for (int n = 0; n < 12; ++n) {
      int colg = c * 192 + n * 16 + l15;
#pragma unroll
      for (int j = 0; j < 4; ++j) {
        int rowg = q0 + r * 16 + l4 * 4 + j;
        obase[(size_t)rowg * D_DIM + colg] = acc[n][j] / l_i[j];
      }
    }
    __syncthreads();  // protect LDS before next half
  }
}

extern "C" void kernel_launch(void* const* d_in, const int* in_sizes, int n_in,
                              void* d_out, int out_size, void* d_ws, size_t ws_size,
                              hipStream_t stream) {
  const float* x = (const float*)d_in[0];
  const float* Wq = (const float*)d_in[1];
  const float* Wk = (const float*)d_in[2];
  const float* Wv = (const float*)d_in[3];
  float* out = (float*)d_out;
  char* ws = (char*)d_ws;

  const size_t XB_SZ = (size_t)M_DIM * D_DIM * 2;  // 25,165,824 B
  short* xb = (short*)(ws);
  short* qkv = (short*)(ws + XB_SZ);
  short* Qb = qkv;
  short* Kb = qkv + (size_t)M_DIM * D_DIM;
  short* Vb = qkv + 2 * (size_t)M_DIM * D_DIM;
  short* VTb = (short*)(ws + 4 * XB_SZ);
  short* WT = (short*)(ws + 5 * XB_SZ);
  // total ws use: 5*XB_SZ + 3*768*768*2 = 129,368,064 B

  cvt_x_kernel<<<dim3(12288), dim3(256), 0, stream>>>(x, xb, M_DIM * D_DIM);
  transpose_w_kernel<<<dim3(12, 12, 3), dim3(256), 0, stream>>>(Wq, Wk, Wv, WT);
  proj_kernel<<<dim3(128, 6, 3), dim3(256), 0, stream>>>(xb, WT, qkv);
  transpose_v_kernel<<<dim3(64, 12, 4), dim3(256), 0, stream>>>(Vb, VTb);
  flash_kernel<<<dim3(256), dim3(512), 0, stream>>>(Qb, Kb, VTb, out);
}

// Round 2
// 768.799 us; speedup vs baseline: 1.3328x; 1.3328x over previous
//
#include <hip/hip_runtime.h>
#include <hip/hip_bf16.h>

typedef __attribute__((ext_vector_type(8))) short short8_t;
typedef __attribute__((ext_vector_type(4))) float float4_t;

#define D_DIM 768
#define S_DIM 4096
#define B_DIM 4
#define M_DIM (B_DIM * S_DIM)  // 16384

__device__ __forceinline__ short f2bf(float f) {
  unsigned u = __float_as_uint(f);
  unsigned r = (u + 0x7fffu + ((u >> 16) & 1u)) >> 16;  // RNE
  return (short)r;
}

#define GLOAD_LDS16(g, s)                                      \
  __builtin_amdgcn_global_load_lds(                            \
      (const __attribute__((address_space(1))) void*)(g),      \
      (__attribute__((address_space(3))) void*)(s), 16, 0, 0)

// ---------------- x -> bf16 (vectorized) ----------------
__global__ __launch_bounds__(256) void cvt_x_kernel(const float* __restrict__ in,
                                                    short* __restrict__ out, int n) {
  int i = (blockIdx.x * 256 + threadIdx.x) * 4;
  if (i < n) {
    float4 v = *(const float4*)(in + i);
    short4 o;
    o.x = f2bf(v.x); o.y = f2bf(v.y); o.z = f2bf(v.z); o.w = f2bf(v.w);
    *(short4*)(out + i) = o;
  }
}

// ---------------- W (fp32 [k][n]) -> WT (bf16 [n][k]) ----------------
__global__ __launch_bounds__(256) void transpose_w_kernel(const float* __restrict__ W0,
                                                          const float* __restrict__ W1,
                                                          const float* __restrict__ W2,
                                                          short* __restrict__ WT) {
  const float* W = (blockIdx.z == 0) ? W0 : (blockIdx.z == 1) ? W1 : W2;
  short* o = WT + (size_t)blockIdx.z * D_DIM * D_DIM;
  __shared__ short tile[64][68];
  int k0 = blockIdx.x * 64, n0 = blockIdx.y * 64;
#pragma unroll
  for (int i = 0; i < 16; ++i) {
    int idx = threadIdx.x + i * 256;
    int r = idx >> 6, c = idx & 63;
    tile[r][c] = f2bf(W[(size_t)(k0 + r) * D_DIM + n0 + c]);
  }
  __syncthreads();
#pragma unroll
  for (int i = 0; i < 16; ++i) {
    int idx = threadIdx.x + i * 256;
    int r = idx >> 6, c = idx & 63;
    o[(size_t)(n0 + r) * D_DIM + k0 + c] = tile[c][r];
  }
}

// ---------------- V (bf16 [s][d]) -> VT (bf16 [d][s]) per batch ----------------
__global__ __launch_bounds__(256) void transpose_v_kernel(const short* __restrict__ Vb,
                                                          short* __restrict__ VTb) {
  __shared__ short tile[64][68];
  int b = blockIdx.z;
  int s0 = blockIdx.x * 64, d0 = blockIdx.y * 64;
  const short* in = Vb + (size_t)b * S_DIM * D_DIM;
  short* o = VTb + (size_t)b * D_DIM * S_DIM;
#pragma unroll
  for (int i = 0; i < 16; ++i) {
    int idx = threadIdx.x + i * 256;
    int rr = idx >> 6, cc = idx & 63;
    tile[rr][cc] = in[(size_t)(s0 + rr) * D_DIM + d0 + cc];
  }
  __syncthreads();
#pragma unroll
  for (int i = 0; i < 16; ++i) {
    int idx = threadIdx.x + i * 256;
    int rr = idx >> 6, cc = idx & 63;
    o[(size_t)(d0 + rr) * S_DIM + s0 + cc] = tile[cc][rr];
  }
}

// ---------------- projections: Y[z] = xb @ WT[z]^T  (bf16 MFMA) ----------------
__global__ __launch_bounds__(256, 2) void proj_kernel(const short* __restrict__ xb,
                                                      const short* __restrict__ WTall,
                                                      short* __restrict__ Yall) {
  const short* WT = WTall + (size_t)blockIdx.z * D_DIM * D_DIM;
  short* Y = Yall + (size_t)blockIdx.z * (size_t)M_DIM * D_DIM;
  int bm = blockIdx.x * 128, bn = blockIdx.y * 128;
  int tid = threadIdx.x;
  int w = tid >> 6, l = tid & 63;
  int wr = w >> 1, wc = w & 1;
  int l15 = l & 15, l4 = l >> 4;
  const float4_t fzero = {0.f, 0.f, 0.f, 0.f};
  float4_t acc[4][4];
#pragma unroll
  for (int a = 0; a < 4; ++a)
#pragma unroll
    for (int bb = 0; bb < 4; ++bb) acc[a][bb] = fzero;
  const short* arow = xb + (size_t)(bm + wr * 64 + l15) * D_DIM + l4 * 8;
  const short* brow = WT + (size_t)(bn + wc * 64 + l15) * D_DIM + l4 * 8;
#pragma unroll 2
  for (int kk = 0; kk < 24; ++kk) {
    short8_t af[4], bf[4];
#pragma unroll
    for (int i = 0; i < 4; ++i)
      af[i] = *(const short8_t*)(arow + (size_t)i * 16 * D_DIM + kk * 32);
#pragma unroll
    for (int i = 0; i < 4; ++i)
      bf[i] = *(const short8_t*)(brow + (size_t)i * 16 * D_DIM + kk * 32);
#pragma unroll
    for (int mi = 0; mi < 4; ++mi)
#pragma unroll
      for (int ni = 0; ni < 4; ++ni)
        acc[mi][ni] = __builtin_amdgcn_mfma_f32_16x16x32_bf16(af[mi], bf[ni], acc[mi][ni], 0, 0, 0);
  }
#pragma unroll
  for (int mi = 0; mi < 4; ++mi) {
#pragma unroll
    for (int ni = 0; ni < 4; ++ni) {
      int colg = bn + wc * 64 + ni * 16 + l15;
#pragma unroll
      for (int j = 0; j < 4; ++j) {
        int rowg = bm + wr * 64 + mi * 16 + l4 * 4 + j;
        Y[(size_t)rowg * D_DIM + colg] = f2bf(acc[mi][ni][j]);
      }
    }
  }
}

// ---------------- flash attention v2: LDS-staged K/VT, D-halves, 1-deep pipeline ----
// grid: 256 blocks (q-tile pairs), 512 threads = 8 waves (r in {0,1}, c in {0..3}).
// QBLK=32, KVBLK=64. K half-tile [64][384] bf16 = 48 KB; VT half [384][64] = 48 KB.
// Two shared buffers A/B alternate: K h0 | K h1 | VT h0 | VT h1 | K' h0 | ...
// All LDS tiles XOR-swizzled ( (row&7)<<4 on byte addr ) for conflict-free b128 reads;
// swizzle applied by pre-swizzling the global source of global_load_lds (linear dest).

// stage K half-tile: buf[row 0..63][d 0..383], row stride 768B
__device__ __forceinline__ void stage_K(char* buf, const short* Kg, int kv0, int dh, int tid) {
#pragma unroll
  for (int i = 0; i < 6; ++i) {
    int L = i * 512 + tid;           // 16B slot index, 48 slots per row
    int row = L / 48;
    int u = L - row * 48;
    int usw = u ^ (row & 7);
    const short* src = Kg + (size_t)(kv0 + row) * D_DIM + dh + usw * 8;
    char* dst = buf + (size_t)(i * 512 + (tid & ~63)) * 16;
    GLOAD_LDS16(src, dst);
  }
}

// stage VT half-tile: buf[drow 0..383][kv 0..63], row stride 128B
__device__ __forceinline__ void stage_VT(char* buf, const short* VTg, int kv0, int dh, int tid) {
#pragma unroll
  for (int i = 0; i < 6; ++i) {
    int L = i * 512 + tid;           // 8 slots per row
    int row = L >> 3;
    int u = (L & 7) ^ (row & 7);
    const short* src = VTg + (size_t)(dh + row) * S_DIM + kv0 + u * 8;
    char* dst = buf + (size_t)(i * 512 + (tid & ~63)) * 16;
    GLOAD_LDS16(src, dst);
  }
}

__global__ __launch_bounds__(512) void flash_kernel(const short* __restrict__ Qb,
                                                    const short* __restrict__ Kb,
                                                    const short* __restrict__ VTb,
                                                    float* __restrict__ out) {
  const float SCALE = 0.036084391824351615f;  // 1/sqrt(768)
  __shared__ __align__(16) char bufA[49152];
  __shared__ __align__(16) char bufB[49152];
  __shared__ __align__(16) char P_lds[4096];
  __shared__ float pmax_s[4][32];
  __shared__ float psum_s[4][32];

  int tid = threadIdx.x;
  int w = tid >> 6;
  int l = tid & 63;
  int r = w >> 2;
  int c = w & 3;
  int l15 = l & 15, l4 = l >> 4;

  int b = blockIdx.x >> 6;
  int pair = blockIdx.x & 63;

  const short* Qbase = Qb + (size_t)b * S_DIM * D_DIM;
  const short* Kbase = Kb + (size_t)b * S_DIM * D_DIM;
  const short* Vtb = VTb + (size_t)b * D_DIM * S_DIM;
  float* obase = out + (size_t)b * S_DIM * D_DIM;

  const float4_t fzero = {0.f, 0.f, 0.f, 0.f};

  // precomputed LDS read bases
  const int krow = c * 16 + l15;
  const int ksw = (krow & 7) << 4;
  const int kbase = krow * 768 + l4 * 16;
  const int prow = r * 16 + l15;
  const int psw = (prow & 7) << 4;
  const int pbase = prow * 128 + l4 * 16;

  // prologue for half 0: stage K(t=0) half0 into A
  stage_K(bufA, Kbase, 0, 0, tid);

  for (int half = 0; half < 2; ++half) {
    int qt = half ? (127 - pair) : pair;
    int q0 = qt * 32;

    // Q fragments for this wave's 16 rows, entire D=768, in registers
    short8_t qf[24];
    {
      const short* qrow = Qbase + (size_t)(q0 + r * 16 + l15) * D_DIM + l4 * 8;
#pragma unroll
      for (int kk = 0; kk < 24; ++kk) qf[kk] = *(const short8_t*)(qrow + kk * 32);
    }
#pragma unroll
    for (int kk = 0; kk < 24; ++kk) {
      asm volatile("" : "+v"(qf[kk]));  // pin in VGPRs; block rematerialization
    }

    float4_t acc[12];
#pragma unroll
    for (int n = 0; n < 12; ++n) acc[n] = fzero;
    float m_i[4], l_i[4];
#pragma unroll
    for (int j = 0; j < 4; ++j) { m_i[j] = -__builtin_inff(); l_i[j] = 0.f; }

    int tmax = (q0 + 31) >> 6;
    for (int t = 0; t <= tmax; ++t) {
      int kv0 = t * 64;

      // ---- P0: K h0 ready in A; stage B <- K h1; QK^T half 0 ----
      __syncthreads();
      stage_K(bufB, Kbase, kv0, 384, tid);
      float4_t s0 = fzero, s1 = fzero;
#pragma unroll
      for (int kk = 0; kk < 12; ++kk) {
        short8_t kf = *(const short8_t*)(bufA + ((kbase + kk * 64) ^ ksw));
        if (kk & 1)
          s1 = __builtin_amdgcn_mfma_f32_16x16x32_bf16(qf[kk], kf, s1, 0, 0, 0);
        else
          s0 = __builtin_amdgcn_mfma_f32_16x16x32_bf16(qf[kk], kf, s0, 0, 0, 0);
      }

      // ---- P1: K h1 ready in B; stage A <- VT h0; QK^T half 1 ----
      __syncthreads();
      stage_VT(bufA, Vtb, kv0, 0, tid);
#pragma unroll
      for (int kk = 0; kk < 12; ++kk) {
        short8_t kf = *(const short8_t*)(bufB + ((kbase + kk * 64) ^ ksw));
        if (kk & 1)
          s1 = __builtin_amdgcn_mfma_f32_16x16x32_bf16(qf[12 + kk], kf, s1, 0, 0, 0);
        else
          s0 = __builtin_amdgcn_mfma_f32_16x16x32_bf16(qf[12 + kk], kf, s0, 0, 0, 0);
      }
      float4_t sc = s0 + s1;
      int colg = kv0 + c * 16 + l15;
#pragma unroll
      for (int j = 0; j < 4; ++j) {
        int rowg = q0 + r * 16 + l4 * 4 + j;
        float sv = sc[j] * SCALE;
        sc[j] = (colg <= rowg) ? sv : -1e30f;
      }
      // partial max over this wave's 16 cols
      float4_t pm = sc;
#pragma unroll
      for (int d = 1; d < 16; d <<= 1) {
#pragma unroll
        for (int j = 0; j < 4; ++j) pm[j] = fmaxf(pm[j], __shfl_xor(pm[j], d));
      }
      if (l15 == 0) {
#pragma unroll
        for (int j = 0; j < 4; ++j) pmax_s[c][r * 16 + l4 * 4 + j] = pm[j];
      }
      __syncthreads();  // SM1: pmax partials visible
      float alpha[4];
#pragma unroll
      for (int j = 0; j < 4; ++j) {
        int rl = r * 16 + l4 * 4 + j;
        float mn = fmaxf(fmaxf(pmax_s[0][rl], pmax_s[1][rl]),
                         fmaxf(pmax_s[2][rl], pmax_s[3][rl]));
        mn = fmaxf(mn, m_i[j]);
        alpha[j] = __expf(m_i[j] - mn);
        m_i[j] = mn;
        sc[j] = __expf(sc[j] - mn);
      }
      float4_t ps = sc;
#pragma unroll
      for (int d = 1; d < 16; d <<= 1) {
#pragma unroll
        for (int j = 0; j < 4; ++j) ps[j] += __shfl_xor(ps[j], d);
      }
      if (l15 == 0) {
#pragma unroll
        for (int j = 0; j < 4; ++j) psum_s[c][r * 16 + l4 * 4 + j] = ps[j];
      }
#pragma unroll
      for (int j = 0; j < 4; ++j) {
        int row = r * 16 + l4 * 4 + j;
        int off = (row * 128 + (c * 16 + l15) * 2) ^ ((row & 7) << 4);
        *(short*)(P_lds + off) = f2bf(sc[j]);
      }

      // ---- P2: VT h0 ready in A (+ P ready); stage B <- VT h1; PV half 0 ----
      __syncthreads();
      stage_VT(bufB, Vtb, kv0, 384, tid);
      short8_t pa0 = *(const short8_t*)(P_lds + (pbase ^ psw));
      short8_t pa1 = *(const short8_t*)(P_lds + ((pbase + 64) ^ psw));
#pragma unroll
      for (int j = 0; j < 4; ++j) {
        int rl = r * 16 + l4 * 4 + j;
        l_i[j] = l_i[j] * alpha[j] +
                 psum_s[0][rl] + psum_s[1][rl] + psum_s[2][rl] + psum_s[3][rl];
      }
#pragma unroll
      for (int n = 0; n < 12; ++n)
#pragma unroll
        for (int j = 0; j < 4; ++j) acc[n][j] *= alpha[j];
#pragma unroll
      for (int mm = 0; mm < 6; ++mm) {
        int m = mm;  // coltile (c + 4*m), d rows [(c+4m)*16, +16) all < 384 for m<6
        int lrow = (c + 4 * m) * 16 + l15;
        int vsw = (lrow & 7) << 4;
        int vb = lrow * 128 + l4 * 16;
        short8_t v0 = *(const short8_t*)(bufA + (vb ^ vsw));
        short8_t v1 = *(const short8_t*)(bufA + ((vb + 64) ^ vsw));
        acc[m] = __builtin_amdgcn_mfma_f32_16x16x32_bf16(pa0, v0, acc[m], 0, 0, 0);
        acc[m] = __builtin_amdgcn_mfma_f32_16x16x32_bf16(pa1, v1, acc[m], 0, 0, 0);
      }

      // ---- P3: VT h1 ready in B; stage A <- next K h0; PV half 1 ----
      __syncthreads();
      int nkv0 = (t < tmax) ? (t + 1) * 64 : ((half == 0) ? 0 : -1);
      if (nkv0 >= 0) stage_K(bufA, Kbase, nkv0, 0, tid);
#pragma unroll
      for (int mm = 0; mm < 6; ++mm) {
        int m = 6 + mm;
        int lrow = (c + 4 * m) * 16 + l15 - 384;
        int vsw = (lrow & 7) << 4;
        int vb = lrow * 128 + l4 * 16;
        short8_t v0 = *(const short8_t*)(bufB + (vb ^ vsw));
        short8_t v1 = *(const short8_t*)(bufB + ((vb + 64) ^ vsw));
        acc[m] = __builtin_amdgcn_mfma_f32_16x16x32_bf16(pa0, v0, acc[m], 0, 0, 0);
        acc[m] = __builtin_amdgcn_mfma_f32_16x16x32_bf16(pa1, v1, acc[m], 0, 0, 0);
      }
    }

    // epilogue: out = acc / l   (coltile of acc[m] is c + 4*m)
#pragma unroll
    for (int m = 0; m < 12; ++m) {
      int colg = (c + 4 * m) * 16 + l15;
#pragma unroll
      for (int j = 0; j < 4; ++j) {
        int rowg = q0 + r * 16 + l4 * 4 + j;
        obase[(size_t)rowg * D_DIM + colg] = acc[m][j] / l_i[j];
      }
    }
  }
}

extern "C" void kernel_launch(void* const* d_in, const int* in_sizes, int n_in,
                              void* d_out, int out_size, void* d_ws, size_t ws_size,
                              hipStream_t stream) {
  const float* x = (const float*)d_in[0];
  const float* Wq = (const float*)d_in[1];
  const float* Wk = (const float*)d_in[2];
  const float* Wv = (const float*)d_in[3];
  float* out = (float*)d_out;
  char* ws = (char*)d_ws;

  const size_t XB_SZ = (size_t)M_DIM * D_DIM * 2;  // 25,165,824 B
  short* xb = (short*)(ws);
  short* qkv = (short*)(ws + XB_SZ);
  short* Qb = qkv;
  short* Kb = qkv + (size_t)M_DIM * D_DIM;
  short* Vb = qkv + 2 * (size_t)M_DIM * D_DIM;
  short* VTb = (short*)(ws + 4 * XB_SZ);
  short* WT = (short*)(ws + 5 * XB_SZ);

  cvt_x_kernel<<<dim3(12288), dim3(256), 0, stream>>>(x, xb, M_DIM * D_DIM);
  transpose_w_kernel<<<dim3(12, 12, 3), dim3(256), 0, stream>>>(Wq, Wk, Wv, WT);
  proj_kernel<<<dim3(128, 6, 3), dim3(256), 0, stream>>>(xb, WT, qkv);
  transpose_v_kernel<<<dim3(64, 12, 4), dim3(256), 0, stream>>>(Vb, VTb);
  flash_kernel<<<dim3(256), dim3(512), 0, stream>>>(Qb, Kb, VTb, out);
}

// Round 4
// 361.342 us; speedup vs baseline: 2.8356x; 2.1276x over previous
//
#include <hip/hip_runtime.h>
#include <hip/hip_bf16.h>

typedef __attribute__((ext_vector_type(8))) _Float16 half8_t;
typedef __attribute__((ext_vector_type(4))) _Float16 half4_t;
typedef __attribute__((ext_vector_type(4))) float float4_t;

#define D_DIM 768
#define S_DIM 4096
#define B_DIM 4
#define M_DIM (B_DIM * S_DIM)  // 16384
#define SD ((size_t)S_DIM * D_DIM)

#define GLOAD_LDS16(g, s)                                      \
  __builtin_amdgcn_global_load_lds(                            \
      (const __attribute__((address_space(1))) void*)(g),      \
      (__attribute__((address_space(3))) void*)(s), 16, 0, 0)

// ---------------- x -> fp16 (vectorized) ----------------
__global__ __launch_bounds__(256) void cvt_x_kernel(const float* __restrict__ in,
                                                    _Float16* __restrict__ out, int n) {
  int i = (blockIdx.x * 256 + threadIdx.x) * 4;
  if (i < n) {
    float4 v = *(const float4*)(in + i);
    half4_t o;
    o.x = (_Float16)v.x; o.y = (_Float16)v.y; o.z = (_Float16)v.z; o.w = (_Float16)v.w;
    *(half4_t*)(out + i) = o;
  }
}

// ---------------- W (fp32 [k][n]) -> WT (fp16 [n][k]) ----------------
__global__ __launch_bounds__(256) void transpose_w_kernel(const float* __restrict__ W0,
                                                          const float* __restrict__ W1,
                                                          const float* __restrict__ W2,
                                                          _Float16* __restrict__ WT) {
  const float* W = (blockIdx.z == 0) ? W0 : (blockIdx.z == 1) ? W1 : W2;
  _Float16* o = WT + (size_t)blockIdx.z * D_DIM * D_DIM;
  __shared__ _Float16 tile[64][68];
  int k0 = blockIdx.x * 64, n0 = blockIdx.y * 64;
#pragma unroll
  for (int i = 0; i < 16; ++i) {
    int idx = threadIdx.x + i * 256;
    int r = idx >> 6, c = idx & 63;
    tile[r][c] = (_Float16)W[(size_t)(k0 + r) * D_DIM + n0 + c];
  }
  __syncthreads();
#pragma unroll
  for (int i = 0; i < 16; ++i) {
    int idx = threadIdx.x + i * 256;
    int r = idx >> 6, c = idx & 63;
    o[(size_t)(n0 + r) * D_DIM + k0 + c] = tile[c][r];
  }
}

// ---------------- V (fp16 [s][d]) -> VT (fp16 [d][s]) per batch (bit-agnostic) ----
__global__ __launch_bounds__(256) void transpose_v_kernel(const short* __restrict__ Vb,
                                                          short* __restrict__ VTb) {
  __shared__ short tile[64][68];
  int b = blockIdx.z;
  int s0 = blockIdx.x * 64, d0 = blockIdx.y * 64;
  const short* in = Vb + (size_t)b * SD;
  short* o = VTb + (size_t)b * SD;
#pragma unroll
  for (int i = 0; i < 16; ++i) {
    int idx = threadIdx.x + i * 256;
    int rr = idx >> 6, cc = idx & 63;
    tile[rr][cc] = in[(size_t)(s0 + rr) * D_DIM + d0 + cc];
  }
  __syncthreads();
#pragma unroll
  for (int i = 0; i < 16; ++i) {
    int idx = threadIdx.x + i * 256;
    int rr = idx >> 6, cc = idx & 63;
    o[(size_t)(d0 + rr) * S_DIM + s0 + cc] = tile[cc][rr];
  }
}

// ---------------- m97-style fp16 GEMM core: 128x128 tile, BK=64, dbuf LDS ----------
// A[m][k] lda, B[n][k] ldb (B^T form). 256 thr = 4 waves (2x2), 4x4 frags each.
// LDS tiles [128][64] fp16, XOR-swizzled via pre-swizzled global source.
__device__ __forceinline__ void gemm_core(const _Float16* __restrict__ Ag,
                                          const _Float16* __restrict__ Bg,
                                          int lda, int ldb, int ksteps,
                                          float4_t acc[4][4]) {
  __shared__ __align__(16) char Ash[2][16384];
  __shared__ __align__(16) char Bsh[2][16384];
  int tid = threadIdx.x;
  int w = tid >> 6, l = tid & 63;
  int wr = w >> 1, wc = w & 1;
  int l15 = l & 15, l4 = l >> 4;

  // staging: granule L = i*256+tid; row=L>>3 (0..127), u=(L&7)^(row&7); 16B granules
  int srow[4], soff[4], sdst[4];
#pragma unroll
  for (int i = 0; i < 4; ++i) {
    int L = i * 256 + tid;
    srow[i] = L >> 3;
    soff[i] = ((L & 7) ^ (srow[i] & 7)) * 8;  // element offset within 64-col slab
    sdst[i] = (i * 256 + (tid & ~63)) * 16;
  }

#define STAGE(kk, buf)                                                        \
  do {                                                                        \
    _Pragma("unroll")                                                         \
    for (int i = 0; i < 4; ++i)                                               \
      GLOAD_LDS16(Ag + (size_t)srow[i] * lda + (kk)*64 + soff[i],             \
                  Ash[buf] + sdst[i]);                                        \
    _Pragma("unroll")                                                         \
    for (int i = 0; i < 4; ++i)                                               \
      GLOAD_LDS16(Bg + (size_t)srow[i] * ldb + (kk)*64 + soff[i],             \
                  Bsh[buf] + sdst[i]);                                        \
  } while (0)

  STAGE(0, 0);
  for (int kk = 0; kk < ksteps; ++kk) {
    int cur = kk & 1;
    __syncthreads();  // drains vmcnt: buf[cur] staged; prev compute done
    if (kk + 1 < ksteps) STAGE(kk + 1, cur ^ 1);
#pragma unroll
    for (int ks = 0; ks < 2; ++ks) {
      half8_t af[4], bf[4];
#pragma unroll
      for (int mi = 0; mi < 4; ++mi) {
        int row = wr * 64 + mi * 16 + l15;
        af[mi] = *(const half8_t*)(Ash[cur] +
                 ((row * 128 + ks * 64 + l4 * 16) ^ ((row & 7) << 4)));
      }
#pragma unroll
      for (int ni = 0; ni < 4; ++ni) {
        int row = wc * 64 + ni * 16 + l15;
        bf[ni] = *(const half8_t*)(Bsh[cur] +
                 ((row * 128 + ks * 64 + l4 * 16) ^ ((row & 7) << 4)));
      }
#pragma unroll
      for (int mi = 0; mi < 4; ++mi)
#pragma unroll
        for (int ni = 0; ni < 4; ++ni)
          acc[mi][ni] = __builtin_amdgcn_mfma_f32_16x16x32_f16(af[mi], bf[ni],
                                                               acc[mi][ni], 0, 0, 0);
    }
  }
#undef STAGE
}

// ---------------- proj: qkv[z] = xh @ WT[z]^T, fp16 out ----------------
__global__ __launch_bounds__(256, 2) void proj_kernel(const _Float16* __restrict__ xh,
                                                      const _Float16* __restrict__ WT,
                                                      _Float16* __restrict__ qkv) {
  int z = blockIdx.z;
  const _Float16* Ag = xh + (size_t)blockIdx.x * 128 * D_DIM;
  const _Float16* Bg = WT + (size_t)z * D_DIM * D_DIM + (size_t)blockIdx.y * 128 * D_DIM;
  const float4_t fz = {0.f, 0.f, 0.f, 0.f};
  float4_t acc[4][4];
#pragma unroll
  for (int a = 0; a < 4; ++a)
#pragma unroll
    for (int b = 0; b < 4; ++b) acc[a][b] = fz;
  gemm_core(Ag, Bg, D_DIM, D_DIM, 12, acc);
  int tid = threadIdx.x;
  int w = tid >> 6, l = tid & 63;
  int wr = w >> 1, wc = w & 1;
  int l15 = l & 15, l4 = l >> 4;
  _Float16* C = qkv + (size_t)z * M_DIM * D_DIM;
#pragma unroll
  for (int mi = 0; mi < 4; ++mi)
#pragma unroll
    for (int ni = 0; ni < 4; ++ni) {
      int col = blockIdx.y * 128 + wc * 64 + ni * 16 + l15;
#pragma unroll
      for (int j = 0; j < 4; ++j) {
        int row = blockIdx.x * 128 + wr * 64 + mi * 16 + l4 * 4 + j;
        C[(size_t)row * D_DIM + col] = (_Float16)acc[mi][ni][j];
      }
    }
}

// ---------------- gemm1: P = exp(scale*QK^T - 4) causal, fp16; rowsum partials ----
// shift-by-4 is softmax-invariant (cancels in P/rowsum); buys fp16 overflow headroom.
__global__ __launch_bounds__(256, 2) void gemm1_kernel(const _Float16* __restrict__ Q,
                                                       const _Float16* __restrict__ K,
                                                       _Float16* __restrict__ P,
                                                       float* __restrict__ rp,
                                                       int row0blk, int nrb) {
  const float SCALE = 0.036084391824351615f;  // 1/sqrt(768)
  const float SHIFT = 4.0f;
  int z = blockIdx.z;
  int rbl = blockIdx.x;             // local row block
  int rbg = row0blk + rbl;          // global row block in batch
  int cb = blockIdx.y;
  if (cb > rbg) return;
  const _Float16* Ag = Q + (size_t)z * SD + (size_t)rbl * 128 * D_DIM;
  const _Float16* Bg = K + (size_t)z * SD + (size_t)cb * 128 * D_DIM;
  const float4_t fz = {0.f, 0.f, 0.f, 0.f};
  float4_t acc[4][4];
#pragma unroll
  for (int a = 0; a < 4; ++a)
#pragma unroll
    for (int b = 0; b < 4; ++b) acc[a][b] = fz;
  gemm_core(Ag, Bg, D_DIM, D_DIM, 12, acc);

  int tid = threadIdx.x;
  int w = tid >> 6, l = tid & 63;
  int wr = w >> 1, wc = w & 1;
  int l15 = l & 15, l4 = l >> 4;
  _Float16* Pz = P + (size_t)z * nrb * 128 * S_DIM;
  float* rpz = rp + (size_t)z * nrb * 128 * 64;
#pragma unroll
  for (int mi = 0; mi < 4; ++mi) {
#pragma unroll
    for (int j = 0; j < 4; ++j) {
      int lrow = rbl * 128 + wr * 64 + mi * 16 + l4 * 4 + j;
      int grow = rbg * 128 + wr * 64 + mi * 16 + l4 * 4 + j;
      float rs = 0.f;
#pragma unroll
      for (int ni = 0; ni < 4; ++ni) {
        int col = cb * 128 + wc * 64 + ni * 16 + l15;
        float v = (col <= grow) ? __expf(acc[mi][ni][j] * SCALE - SHIFT) : 0.f;
        _Float16 ph = (_Float16)v;
        Pz[(size_t)lrow * S_DIM + col] = ph;
        rs += (float)ph;
      }
      // reduce rs over the 16-lane col group
#pragma unroll
      for (int d = 1; d < 16; d <<= 1) rs += __shfl_xor(rs, d);
      if (l15 == 0) rpz[(size_t)lrow * 64 + cb * 2 + wc] = rs;
    }
  }
}

// ---------------- rsum combine (deterministic) ----------------
__global__ __launch_bounds__(256) void rsum_combine_kernel(const float* __restrict__ rp,
                                                           float* __restrict__ rsum,
                                                           int row0blk, int nrb) {
  int idx = blockIdx.x * 256 + threadIdx.x;  // z*rows + lrow
  int rows = nrb * 128;
  int z = idx / rows;
  int lrow = idx - z * rows;
  int rbg = row0blk + (lrow >> 7);
  int np = 2 * (rbg + 1);
  const float* p = rp + (size_t)idx * 64;
  float s = 0.f;
  for (int i = 0; i < np; ++i) s += p[i];
  rsum[idx] = s;
}

// ---------------- gemm2: out = (P @ VT^T) / rsum, f32 out ----------------
__global__ __launch_bounds__(256, 2) void gemm2_kernel(const _Float16* __restrict__ P,
                                                       const _Float16* __restrict__ VT,
                                                       float* __restrict__ outp,
                                                       const float* __restrict__ rsum,
                                                       int row0blk, int nrb) {
  int z = blockIdx.z;
  int bxx = nrb - 1 - blockIdx.x;   // heavy blocks first
  int rbg = row0blk + bxx;
  const _Float16* Ag = P + (size_t)z * nrb * 128 * S_DIM + (size_t)bxx * 128 * S_DIM;
  const _Float16* Bg = VT + (size_t)z * SD + (size_t)blockIdx.y * 128 * S_DIM;
  int ksteps = (rbg + 1) * 2;
  const float4_t fz = {0.f, 0.f, 0.f, 0.f};
  float4_t acc[4][4];
#pragma unroll
  for (int a = 0; a < 4; ++a)
#pragma unroll
    for (int b = 0; b < 4; ++b) acc[a][b] = fz;
  gemm_core(Ag, Bg, S_DIM, S_DIM, ksteps, acc);

  int tid = threadIdx.x;
  int w = tid >> 6, l = tid & 63;
  int wr = w >> 1, wc = w & 1;
  int l15 = l & 15, l4 = l >> 4;
  float* Cz = outp + (size_t)z * SD + (size_t)bxx * 128 * D_DIM;  // row-block base
  const float* rsz = rsum + (size_t)z * nrb * 128;
#pragma unroll
  for (int mi = 0; mi < 4; ++mi) {
#pragma unroll
    for (int j = 0; j < 4; ++j) {
      int lrow_in = wr * 64 + mi * 16 + l4 * 4 + j;  // row within this 128-row block
      float rinv = 1.0f / rsz[(size_t)bxx * 128 + lrow_in];
#pragma unroll
      for (int ni = 0; ni < 4; ++ni) {
        int col = blockIdx.y * 128 + wc * 64 + ni * 16 + l15;
        Cz[(size_t)lrow_in * D_DIM + col] = acc[mi][ni][j] * rinv;
      }
    }
  }
}

extern "C" void kernel_launch(void* const* d_in, const int* in_sizes, int n_in,
                              void* d_out, int out_size, void* d_ws, size_t ws_size,
                              hipStream_t stream) {
  const float* x = (const float*)d_in[0];
  const float* Wq = (const float*)d_in[1];
  const float* Wk = (const float*)d_in[2];
  const float* Wv = (const float*)d_in[3];
  float* out = (float*)d_out;
  char* ws = (char*)d_ws;

  const size_t XH_B = (size_t)M_DIM * D_DIM * 2;        // 25,165,824
  const size_t QKV_B = 3 * XH_B;                         // 75,497,472
  const size_t VT_B = XH_B;                              // 25,165,824
  const size_t WT_B = (size_t)3 * D_DIM * D_DIM * 2;     // 3,538,944
  const size_t BASE_END = XH_B + QKV_B + VT_B + WT_B;    // 129,368,064 (proven avail)

  _Float16* xh = (_Float16*)ws;
  _Float16* qkv = (_Float16*)(ws + XH_B);
  _Float16* Q = qkv;
  _Float16* K = qkv + (size_t)M_DIM * D_DIM;
  _Float16* V = qkv + 2 * (size_t)M_DIM * D_DIM;
  _Float16* vt = (_Float16*)(ws + XH_B + QKV_B);
  _Float16* wt = (_Float16*)(ws + XH_B + QKV_B + VT_B);

  cvt_x_kernel<<<dim3(12288), dim3(256), 0, stream>>>(x, xh, M_DIM * D_DIM);
  transpose_w_kernel<<<dim3(12, 12, 3), dim3(256), 0, stream>>>(Wq, Wk, Wv, wt);
  proj_kernel<<<dim3(128, 6, 3), dim3(256), 0, stream>>>(xh, wt, qkv);
  transpose_v_kernel<<<dim3(64, 12, 4), dim3(256), 0, stream>>>((const short*)V, (short*)vt);

  const size_t P_BATCH = (size_t)S_DIM * S_DIM * 2;      // 33,554,432
  const size_t RP_BATCH = (size_t)S_DIM * 64 * 4;        // 1,048,576
  const size_t RS_BATCH = (size_t)S_DIM * 4;             // 16,384
  const size_t NEED_A = BASE_END + 4 * RP_BATCH + 4 * RS_BATCH + 4 * P_BATCH;
  const size_t NEED_B = BASE_END + RP_BATCH + RS_BATCH + P_BATCH;

  if (ws_size >= NEED_A) {
    // all 4 batches in one go
    float* rp = (float*)(ws + BASE_END);
    float* rsum = (float*)(ws + BASE_END + 4 * RP_BATCH);
    _Float16* P = (_Float16*)(ws + BASE_END + 4 * RP_BATCH + 4 * RS_BATCH);
    gemm1_kernel<<<dim3(32, 32, 4), dim3(256), 0, stream>>>(Q, K, P, rp, 0, 32);
    rsum_combine_kernel<<<dim3(64), dim3(256), 0, stream>>>(rp, rsum, 0, 32);
    gemm2_kernel<<<dim3(32, 6, 4), dim3(256), 0, stream>>>(P, vt, out, rsum, 0, 32);
  } else if (ws_size >= NEED_B) {
    // per-batch
    float* rp = (float*)(ws + BASE_END);
    float* rsum = (float*)(ws + BASE_END + RP_BATCH);
    _Float16* P = (_Float16*)(ws + BASE_END + RP_BATCH + RS_BATCH);
    for (int b = 0; b < 4; ++b) {
      gemm1_kernel<<<dim3(32, 32, 1), dim3(256), 0, stream>>>(Q + b * SD, K + b * SD, P, rp, 0, 32);
      rsum_combine_kernel<<<dim3(16), dim3(256), 0, stream>>>(rp, rsum, 0, 32);
      gemm2_kernel<<<dim3(32, 6, 1), dim3(256), 0, stream>>>(P, vt + b * SD, out + b * SD, rsum, 0, 32);
    }
  } else {
    // P/rp/rsum overlaid on xh (dead after proj): 8 chunks of 2048 rows
    _Float16* P = (_Float16*)ws;
    float* rp = (float*)(ws + (size_t)2048 * S_DIM * 2);
    float* rsum = (float*)(ws + (size_t)2048 * S_DIM * 2 + (size_t)2048 * 64 * 4);
    for (int b = 0; b < 4; ++b) {
      for (int h = 0; h < 2; ++h) {
        int row0 = h * 16;
        gemm1_kernel<<<dim3(16, (h + 1) * 16, 1), dim3(256), 0, stream>>>(
            Q + b * SD + (size_t)row0 * 128 * D_DIM, K + b * SD, P, rp, row0, 16);
        rsum_combine_kernel<<<dim3(8), dim3(256), 0, stream>>>(rp, rsum, row0, 16);
        gemm2_kernel<<<dim3(16, 6, 1), dim3(256), 0, stream>>>(
            P, vt + b * SD, out + b * SD + (size_t)row0 * 128 * D_DIM, rsum, row0, 16);
      }
    }
  }
}